// Round 10
// baseline (173.363 us; speedup 1.0000x reference)
//
#include <hip/hip_runtime.h>
#include <hip/hip_bf16.h>

typedef __bf16 bf16;
typedef __bf16 bf16x8 __attribute__((ext_vector_type(8)));
typedef __bf16 bf16x4 __attribute__((ext_vector_type(4)));
typedef float  f32x4  __attribute__((ext_vector_type(4)));

static constexpr int SDIM = 2048;
static constexpr int EDIM = 512;
static constexpr int HDIM = 64;

typedef __attribute__((address_space(1))) const void* gptr_t;
typedef __attribute__((address_space(3))) void*       lptr_t;

__device__ __forceinline__ void gl_lds16(const bf16* g, bf16* l) {
  __builtin_amdgcn_global_load_lds((gptr_t)g, (lptr_t)l, 16, 0, 0);
}

#if __has_builtin(__builtin_amdgcn_exp2f)
#define EXP2F(x) __builtin_amdgcn_exp2f(x)
#else
#define EXP2F(x) exp2f(x)
#endif

__device__ __forceinline__ bf16x8 pack8(f32x4 a, f32x4 b) {
  bf16x8 r;
  r[0] = (bf16)a[0]; r[1] = (bf16)a[1]; r[2] = (bf16)a[2]; r[3] = (bf16)a[3];
  r[4] = (bf16)b[0]; r[5] = (bf16)b[1]; r[6] = (bf16)b[2]; r[7] = (bf16)b[3];
  return r;
}

// ---------------------------------------------------------------------------
// Kernel A: W (f32 [512][64]) -> Wt (bf16 [64][512]) via LDS transpose.
// Wq scaled by 0.125*log2(e): scores exit QK^T in log2 units (bare exp2).
// ---------------------------------------------------------------------------
__global__ __launch_bounds__(256) void wt_kernel(const float* __restrict__ Wq,
                                                 const float* __restrict__ Wk,
                                                 const float* __restrict__ Wv,
                                                 bf16* __restrict__ Wt) {
  __shared__ float lds[64][65];
  const int mat = blockIdx.x >> 3;
  const int et  = blockIdx.x & 7;
  const float* W = (mat == 0) ? Wq : ((mat == 1) ? Wk : Wv);
  const float scale = (mat == 0) ? 0.18033688f : 1.0f;   // 0.125 * log2(e)
  const int t  = threadIdx.x;
  const int er = t >> 2;
  const int c4 = (t & 3) * 16;
#pragma unroll
  for (int j = 0; j < 4; ++j) {
    f32x4 v = *(const f32x4*)(W + (size_t)(et * 64 + er) * HDIM + c4 + j * 4);
    lds[er][c4 + j * 4 + 0] = v[0]; lds[er][c4 + j * 4 + 1] = v[1];
    lds[er][c4 + j * 4 + 2] = v[2]; lds[er][c4 + j * 4 + 3] = v[3];
  }
  __syncthreads();
  const int h  = t >> 2;
  const int ec = (t & 3) * 16;
  bf16x8 o0, o1;
#pragma unroll
  for (int j = 0; j < 8; ++j) o0[j] = (bf16)(lds[ec + j][h] * scale);
#pragma unroll
  for (int j = 0; j < 8; ++j) o1[j] = (bf16)(lds[ec + 8 + j][h] * scale);
  bf16* dst = Wt + mat * (HDIM * EDIM) + (size_t)h * EDIM + et * 64 + ec;
  *(bf16x8*)dst = o0;
  *(bf16x8*)(dst + 8) = o1;
}

// ---------------------------------------------------------------------------
// Kernel B: fused QKV projection (round-9 shape, unchanged): Wt LDS-staged
// in 2-ks chunks (8 barriers), x raw-prefetched f32x4s converted a chunk
// late (no in-loop vmcnt(0) drain). Block 64 rows, grid 512 -> 2 blocks/CU.
// ---------------------------------------------------------------------------
__global__ __launch_bounds__(256) void proj_kernel(const float* __restrict__ x,
                                                   const bf16* __restrict__ Wt,
                                                   const int* __restrict__ lens,
                                                   bf16* __restrict__ qo,
                                                   bf16* __restrict__ ko,
                                                   bf16* __restrict__ vT) {
  __shared__ __align__(16) bf16 wbuf[2][192 * 64];   // [m*64+h][e 0..63] swz
  const int tid  = threadIdx.x;
  const int wave = tid >> 6;
  const int lane = tid & 63;
  const int quad = lane >> 4;
  const int l16  = lane & 15;
  const int rowbase = blockIdx.x * 64 + wave * 16;
  const int b = blockIdx.x >> 5;                     // 32 blocks per batch
  const float* xrow = x + (size_t)(rowbase + l16) * EDIM + quad * 8;
  const int srow   = lane >> 3;                      // 0..7
  const int schunk = (lane & 7) ^ srow;              // global chunk to fetch

  #define WSTAGE(ck, buf) { _Pragma("unroll")                                  \
    for (int i6 = 0; i6 < 6; ++i6) {                                           \
      const int R0 = (wave * 6 + i6) * 8;                                      \
      gl_lds16(Wt + (size_t)(R0 + srow) * EDIM + (ck) * 64 + schunk * 8,       \
               &(buf)[R0 * 64]); } }

  f32x4 acc[3][4];
#pragma unroll
  for (int m = 0; m < 3; ++m)
#pragma unroll
    for (int nt = 0; nt < 4; ++nt) acc[m][nt] = (f32x4){0.f, 0.f, 0.f, 0.f};

  #define WCOMPUTE(buf, eo4, afrag) { _Pragma("unroll")                        \
    for (int m = 0; m < 3; ++m) { _Pragma("unroll")                            \
      for (int nt = 0; nt < 4; ++nt) {                                         \
        bf16x8 bfv = *(const bf16x8*)(&(buf)[(m * 64 + nt * 16 + l16) * 64 +   \
                                             ((((eo4) + quad) ^ (l16 & 7)) * 8)]); \
        acc[m][nt] = __builtin_amdgcn_mfma_f32_16x16x32_bf16(afrag, bfv, acc[m][nt], 0, 0, 0); } } }

  WSTAGE(0, wbuf[0]);
  f32x4 xA0 = *(const f32x4*)(xrow);
  f32x4 xB0 = *(const f32x4*)(xrow + 4);
  f32x4 xA1 = *(const f32x4*)(xrow + 32);
  f32x4 xB1 = *(const f32x4*)(xrow + 36);
#pragma unroll 2
  for (int ck = 0; ck < 8; ++ck) {
    __syncthreads();                       // wbuf[ck&1] staged
    const int ksn = (ck < 7) ? (ck + 1) * 2 : 14;   // clamp tail (redundant ld)
    f32x4 nA0 = *(const f32x4*)(xrow + ksn * 32);
    f32x4 nB0 = *(const f32x4*)(xrow + ksn * 32 + 4);
    f32x4 nA1 = *(const f32x4*)(xrow + ksn * 32 + 32);
    f32x4 nB1 = *(const f32x4*)(xrow + ksn * 32 + 36);
    if (ck + 1 < 8) WSTAGE(ck + 1, wbuf[(ck + 1) & 1]);
    bf16x8 a = pack8(xA0, xB0);            // data from PREVIOUS chunk: no wait
    WCOMPUTE(wbuf[ck & 1], 0, a);
    a = pack8(xA1, xB1);
    WCOMPUTE(wbuf[ck & 1], 4, a);
    xA0 = nA0; xB0 = nB0; xA1 = nA1; xB1 = nB1;
  }

  int odd_or = 0;
#pragma unroll
  for (int i = 1; i < 16; i += 2) odd_or |= lens[i];
  const int len = (odd_or == 0) ? lens[2 * b] : lens[b];

#pragma unroll
  for (int nt = 0; nt < 4; ++nt) {
    const int h = nt * 16 + l16;
    bf16x4 vv;
#pragma unroll
    for (int r = 0; r < 4; ++r) {
      const int row = rowbase + quad * 4 + r;        // C-layout row = quad*4+reg
      const int s = row & (SDIM - 1);
      const bool pad = (s >= len);
      qo[(size_t)row * HDIM + h] = (bf16)(pad ? 0.f : acc[0][nt][r]);
      ko[(size_t)row * HDIM + h] = (bf16)(pad ? 0.f : acc[1][nt][r]);
      vv[r] = (bf16)acc[2][nt][r];                   // v NOT masked
    }
    *(bf16x4*)(vT + ((size_t)b * HDIM + h) * SDIM + (rowbase & (SDIM - 1)) + quad * 4) = vv;
  }
  #undef WSTAGE
  #undef WCOMPUTE
}

// ---------------------------------------------------------------------------
// Kernel C: flash attention, K LDS-staged, V DIRECT-LOADED, deferred PV.
// Round-9 model: attn is LDS-read-pipe bound (18 b128/wave-step x 8 waves
// x 32 steps x 12cyc ~ 55k cyc/CU). V's fragment pattern is a clean global
// access, so V skips LDS: direct b128 loads, double-register-buffered with
// 2 steps of slack (deferred-PV provides it). LDS reads drop to 10/wave-step
// (kf 8 + pa 2); V comes 4x-redundantly from L2 (~512MB, different pipe).
// 64 q/block (16/wave), grid 512 -> 2 blocks/CU; shift-free softmax;
// XCD decode (2 batches/XCD keeps K/V L2-resident).
// ---------------------------------------------------------------------------
__global__ __launch_bounds__(256) void attn_kernel(const bf16* __restrict__ qb,
                                                   const bf16* __restrict__ kb,
                                                   const bf16* __restrict__ vT,
                                                   float* __restrict__ out) {
  __shared__ __align__(16) bf16 Kbuf[2][64 * 64];
  __shared__ __align__(16) bf16 plds[4][2][16 * 64];  // wave-private P dbuf
  const int tid  = threadIdx.x;
  const int wave = tid >> 6;
  const int lane = tid & 63;
  const int quad = lane >> 4;
  const int l16  = lane & 15;
  const int xcd = blockIdx.x & 7;
  const int jj  = blockIdx.x >> 3;
  const int b   = xcd * 2 + (jj >> 5);
  const int qbase = (jj & 31) * 64 + wave * 16;
  const bf16* q0 = qb + (size_t)b * SDIM * HDIM;
  const bf16* k0 = kb + (size_t)b * SDIM * HDIM;
  const bf16* v0 = vT + (size_t)b * HDIM * SDIM;
  const int swz = (l16 & 7) << 3;
  const int srow   = lane >> 3;
  const int schunk = (lane & 7) ^ (srow & 7);

  bf16x8 qf[2];
#pragma unroll
  for (int c = 0; c < 2; ++c)
    qf[c] = *(const bf16x8*)(q0 + (size_t)(qbase + l16) * HDIM + c * 32 + quad * 8);

  f32x4 O[4];
  float l_acc = 0.f;
#pragma unroll
  for (int ht = 0; ht < 4; ++ht) O[ht] = (f32x4){0.f, 0.f, 0.f, 0.f};

  #define STAGEK(sidx, KB)                                                     \
    {                                                                          \
      const int key0_ = (sidx) * 64;                                           \
      _Pragma("unroll")                                                        \
      for (int j8 = 0; j8 < 2; ++j8) {                                         \
        const int r0 = wave * 16 + j8 * 8;                                     \
        gl_lds16(k0 + (size_t)(key0_ + r0 + srow) * HDIM + schunk * 8,         \
                 &(KB)[r0 * 64]);                                              \
      }                                                                        \
    }

  // V direct loads: B[k=key=quad*8+j][n=h=l16] straight from vT (global)
  #define VLOAD(sidx, dst)                                                     \
    {                                                                          \
      const int key0_ = (sidx) * 64;                                           \
      _Pragma("unroll")                                                        \
      for (int ht = 0; ht < 4; ++ht)                                           \
        _Pragma("unroll")                                                      \
        for (int kc = 0; kc < 2; ++kc)                                         \
          dst[ht][kc] = *(const bf16x8*)(v0 + (size_t)(ht * 16 + l16) * SDIM + \
                                         key0_ + kc * 32 + quad * 8);          \
    }

  bf16x8 vv[2][4][2];       // V register double-buffer (2 steps of slack)
  STAGEK(0, Kbuf[0]);
  VLOAD(0, vv[0]);
#pragma unroll 2
  for (int s = 0; s < 32; ++s) {
    __syncthreads();                       // Kbuf[s&1] staged
    if (s + 1 < 32) STAGEK(s + 1, Kbuf[(s + 1) & 1]);
    const bf16* KB = Kbuf[s & 1];
    bf16* PW = &plds[wave][s & 1][0];
    const bf16* PR = &plds[wave][(s & 1) ^ 1][0];

    // deferred PV for step s-1 first (P written last step, V loaded 2 ago)
    if (s) {
      bf16x8 pa[2];
#pragma unroll
      for (int kc = 0; kc < 2; ++kc)
        pa[kc] = *(const bf16x8*)(&PR[l16 * 64 + (((kc * 4 + quad) << 3) ^ swz)]);
#pragma unroll
      for (int ht = 0; ht < 4; ++ht) {
        O[ht] = __builtin_amdgcn_mfma_f32_16x16x32_bf16(pa[0], vv[(s - 1) & 1][ht][0], O[ht], 0, 0, 0);
        O[ht] = __builtin_amdgcn_mfma_f32_16x16x32_bf16(pa[1], vv[(s - 1) & 1][ht][1], O[ht], 0, 0, 0);
      }
    }
    // now the (s-1)&1 slot is free: prefetch V_{s+1} into it (used at s+2)
    if (s + 1 < 32) VLOAD(s + 1, vv[(s + 1) & 1]);

    bf16x8 kf[4][2];
#pragma unroll
    for (int kt = 0; kt < 4; ++kt)
#pragma unroll
      for (int c = 0; c < 2; ++c)
        kf[kt][c] = *(const bf16x8*)(&KB[(kt * 16 + l16) * 64 + (((c * 4 + quad) << 3) ^ swz)]);

    // QK^T (S^T form), exp2, write P_s
#pragma unroll
    for (int kt = 0; kt < 4; ++kt) {
      f32x4 st = (f32x4){0.f, 0.f, 0.f, 0.f};
      st = __builtin_amdgcn_mfma_f32_16x16x32_bf16(kf[kt][0], qf[0], st, 0, 0, 0);
      st = __builtin_amdgcn_mfma_f32_16x16x32_bf16(kf[kt][1], qf[1], st, 0, 0, 0);
      f32x4 p;
      p[0] = EXP2F(st[0]); p[1] = EXP2F(st[1]);
      p[2] = EXP2F(st[2]); p[3] = EXP2F(st[3]);
      l_acc += (p[0] + p[1]) + (p[2] + p[3]);
      bf16x4 pb;
      pb[0] = (bf16)p[0]; pb[1] = (bf16)p[1]; pb[2] = (bf16)p[2]; pb[3] = (bf16)p[3];
      const int coff = (((kt * 2 + (quad >> 1)) << 3) ^ swz) + (quad & 1) * 4;
      *(bf16x4*)(&PW[l16 * 64 + coff]) = pb;
    }
  }

  // final PV (step 31; P in buffer 1, V_31 in vv[1])
  {
    __builtin_amdgcn_s_waitcnt(0xc07f);   // lgkmcnt(0): P_31 ds_write RAW
    bf16x8 pa[2];
    const bf16* PR = &plds[wave][1][0];
#pragma unroll
    for (int kc = 0; kc < 2; ++kc)
      pa[kc] = *(const bf16x8*)(&PR[l16 * 64 + (((kc * 4 + quad) << 3) ^ swz)]);
#pragma unroll
    for (int ht = 0; ht < 4; ++ht) {
      O[ht] = __builtin_amdgcn_mfma_f32_16x16x32_bf16(pa[0], vv[1][ht][0], O[ht], 0, 0, 0);
      O[ht] = __builtin_amdgcn_mfma_f32_16x16x32_bf16(pa[1], vv[1][ht][1], O[ht], 0, 0, 0);
    }
  }

  // l: butterfly across quads; broadcast per-row inverse via shfl
  l_acc += __shfl_xor(l_acc, 16);
  l_acc += __shfl_xor(l_acc, 32);
  const float inv_own = 1.0f / l_acc;      // l >= 1 always
#pragma unroll
  for (int r = 0; r < 4; ++r) {
    const float inv = __shfl(inv_own, (lane & 48) + quad * 4 + r);
    const int row = qbase + quad * 4 + r;
#pragma unroll
    for (int ht = 0; ht < 4; ++ht)
      out[((size_t)b * SDIM + row) * HDIM + ht * 16 + l16] = O[ht][r] * inv;
  }
  #undef STAGEK
  #undef VLOAD
}

// ---------------------------------------------------------------------------
extern "C" void kernel_launch(void* const* d_in, const int* in_sizes, int n_in,
                              void* d_out, int out_size, void* d_ws, size_t ws_size,
                              hipStream_t stream) {
  (void)in_sizes; (void)n_in; (void)out_size; (void)ws_size;
  const float* x  = (const float*)d_in[0];
  const int*   sl = (const int*)d_in[1];
  const float* Wq = (const float*)d_in[2];
  const float* Wk = (const float*)d_in[3];
  const float* Wv = (const float*)d_in[4];
  float* out = (float*)d_out;

  char* ws = (char*)d_ws;
  bf16* Wt = (bf16*)(ws);                              // 192 KB
  bf16* qb = (bf16*)(ws + (256 << 10));                // 4 MB
  bf16* kb = (bf16*)(ws + (256 << 10) + (4 << 20));    // 4 MB
  bf16* vT = (bf16*)(ws + (256 << 10) + (8 << 20));    // 4 MB ([B][64][S])

  wt_kernel  <<<24,  256, 0, stream>>>(Wq, Wk, Wv, Wt);
  proj_kernel<<<512, 256, 0, stream>>>(x, Wt, sl, qb, kb, vT);
  attn_kernel<<<512, 256, 0, stream>>>(qb, kb, vT, out);
}